// Round 1
// baseline (6516.017 us; speedup 1.0000x reference)
//
#include <hip/hip_runtime.h>
#include <cfloat>

#define NROWS  4096
#define DIM    768
#define KCODES 65536

#define TM 128          // rows per workgroup tile
#define TC 128          // codes per tile
#define DK 16           // D-chunk staged in LDS
#define GROUP_TILES 8   // code tiles per workgroup (1024 codes)
#define GROUPS 64       // KCODES / (TC*GROUP_TILES)
#define ROWTILES 32     // NROWS / TM

// workspace layout (bytes)
#define WS_ZSQ   0
#define WS_PARTD (16384)
#define WS_PARTI (WS_PARTD + NROWS*GROUPS*4)
#define WS_CODES (WS_PARTI + NROWS*GROUPS*4)
#define WS_LOSS  (WS_CODES + NROWS*4)

// ---------------- kernel 0: z_sq per row, zero loss accumulator ------------
__global__ void k0_zsq(const float* __restrict__ z, float* __restrict__ zsq,
                       double* __restrict__ loss) {
  const int wave = threadIdx.x >> 6;
  const int lane = threadIdx.x & 63;
  const int row  = blockIdx.x * 4 + wave;
  const float* zr = z + (size_t)row * DIM;
  float s = 0.f;
  #pragma unroll
  for (int i = 0; i < DIM / 64; ++i) {
    float v = zr[lane + i * 64];
    s = fmaf(v, v, s);
  }
  #pragma unroll
  for (int off = 32; off; off >>= 1) s += __shfl_xor(s, off, 64);
  if (lane == 0) zsq[row] = s;
  if (blockIdx.x == 0 && threadIdx.x == 0) *loss = 0.0;
}

// ---------------- kernel 1: fused fp32 GEMM + per-row argmin ----------------
// grid: (GROUPS, ROWTILES), block: 256 threads (16x16), 8x8 per-thread tile.
__global__ __launch_bounds__(256) void k1_argmin_gemm(
    const float* __restrict__ z, const float* __restrict__ cb,
    const float* __restrict__ zsq,
    float* __restrict__ part_d, int* __restrict__ part_i) {
  __shared__ float As[DK][TM + 4];
  __shared__ float Bs[DK][TC + 4];
  __shared__ float red_d[TM][17];
  __shared__ int   red_i[TM][17];
  __shared__ float best_d[TM];
  __shared__ int   best_i[TM];

  const int tid = threadIdx.x;
  const int tx = tid & 15;        // code sub-tile
  const int ty = tid >> 4;        // row sub-tile
  const int group = blockIdx.x;
  const int row0  = blockIdx.y * TM;

  if (tid < TM) { best_d[tid] = FLT_MAX; best_i[tid] = 0x7fffffff; }

  float zs[8];
  #pragma unroll
  for (int i = 0; i < 8; ++i) zs[i] = zsq[row0 + ty * 8 + i];

  // staging map: thread -> (row = tid/4 + it*64, col4 = (tid&3)*4)
  const int arow = tid >> 2;
  const int acol = (tid & 3) * 4;

  for (int t = 0; t < GROUP_TILES; ++t) {
    const int code0 = group * (TC * GROUP_TILES) + t * TC;
    float acc[8][8];
    #pragma unroll
    for (int i = 0; i < 8; ++i)
      #pragma unroll
      for (int j = 0; j < 8; ++j) acc[i][j] = 0.f;

    for (int kd = 0; kd < DIM; kd += DK) {
      __syncthreads();
      #pragma unroll
      for (int it = 0; it < 2; ++it) {
        const int r = arow + it * 64;
        float4 va = *(const float4*)(z  + (size_t)(row0  + r) * DIM + kd + acol);
        As[acol + 0][r] = va.x; As[acol + 1][r] = va.y;
        As[acol + 2][r] = va.z; As[acol + 3][r] = va.w;
        float4 vb = *(const float4*)(cb + (size_t)(code0 + r) * DIM + kd + acol);
        Bs[acol + 0][r] = vb.x; Bs[acol + 1][r] = vb.y;
        Bs[acol + 2][r] = vb.z; Bs[acol + 3][r] = vb.w;
      }
      __syncthreads();
      #pragma unroll
      for (int k = 0; k < DK; ++k) {
        float a[8], b[8];
        float4 u;
        u = *(const float4*)(&As[k][ty * 8]);     a[0]=u.x; a[1]=u.y; a[2]=u.z; a[3]=u.w;
        u = *(const float4*)(&As[k][ty * 8 + 4]); a[4]=u.x; a[5]=u.y; a[6]=u.z; a[7]=u.w;
        u = *(const float4*)(&Bs[k][tx * 8]);     b[0]=u.x; b[1]=u.y; b[2]=u.z; b[3]=u.w;
        u = *(const float4*)(&Bs[k][tx * 8 + 4]); b[4]=u.x; b[5]=u.y; b[6]=u.z; b[7]=u.w;
        #pragma unroll
        for (int i = 0; i < 8; ++i)
          #pragma unroll
          for (int j = 0; j < 8; ++j)
            acc[i][j] = fmaf(a[i], b[j], acc[i][j]);
      }
    }

    // epilogue: d = fl(z_sq - 2*dot)  (fma(-2,acc,zs) is bit-identical since 2*acc is exact)
    #pragma unroll
    for (int i = 0; i < 8; ++i) {
      float md = FLT_MAX; int mi = 0x7fffffff;
      #pragma unroll
      for (int j = 0; j < 8; ++j) {
        float dv = fmaf(-2.0f, acc[i][j], zs[i]);
        int ci = code0 + tx * 8 + j;
        if (dv < md) { md = dv; mi = ci; }   // ascending j => strict < keeps first index
      }
      red_d[ty * 8 + i][tx] = md;
      red_i[ty * 8 + i][tx] = mi;
    }
    __syncthreads();
    if (tid < TM) {
      float bd = best_d[tid]; int bi = best_i[tid];
      #pragma unroll
      for (int x = 0; x < 16; ++x) {   // ascending x => ascending code index
        float dv = red_d[tid][x]; int ci = red_i[tid][x];
        if (dv < bd || (dv == bd && ci < bi)) { bd = dv; bi = ci; }
      }
      best_d[tid] = bd; best_i[tid] = bi;
    }
  }
  __syncthreads();
  if (tid < TM) {
    part_d[(size_t)(row0 + tid) * GROUPS + group] = best_d[tid];
    part_i[(size_t)(row0 + tid) * GROUPS + group] = best_i[tid];
  }
}

// ---------------- kernel 2: reduce partials -> codes ------------------------
__global__ void k2_reduce(const float* __restrict__ part_d, const int* __restrict__ part_i,
                          float* __restrict__ out_codes, int* __restrict__ codes_i) {
  const int wave = threadIdx.x >> 6;
  const int lane = threadIdx.x & 63;
  const int row = blockIdx.x * 4 + wave;
  float d = part_d[(size_t)row * GROUPS + lane];
  int   i = part_i[(size_t)row * GROUPS + lane];
  #pragma unroll
  for (int off = 32; off; off >>= 1) {
    float od = __shfl_xor(d, off, 64);
    int   oi = __shfl_xor(i, off, 64);
    if (od < d || (od == d && oi < i)) { d = od; i = oi; }  // lexicographic (d, idx) min
  }
  if (lane == 0) { out_codes[row] = (float)i; codes_i[row] = i; }
}

// ---------------- kernel 3: gather + STE + loss sum -------------------------
__global__ void k3_quant_loss(const float* __restrict__ z, const float* __restrict__ cb,
                              const int* __restrict__ codes, float* __restrict__ outq,
                              double* __restrict__ loss) {
  const int gid = blockIdx.x * blockDim.x + threadIdx.x;
  const int e0 = gid * 4;
  const int row = e0 / DIM;
  const int col = e0 - row * DIM;
  const int c = codes[row];
  const float4 zv = *(const float4*)(z + e0);
  const float4 qv = *(const float4*)(cb + (size_t)c * DIM + col);
  float d0 = qv.x - zv.x, d1 = qv.y - zv.y, d2 = qv.z - zv.z, d3 = qv.w - zv.w;
  float4 ov = { zv.x + d0, zv.y + d1, zv.z + d2, zv.w + d3 };  // fl(z + fl(q-z))
  *(float4*)(outq + e0) = ov;
  double s = (double)(d0 * d0) + (double)(d1 * d1) + (double)(d2 * d2) + (double)(d3 * d3);
  #pragma unroll
  for (int off = 32; off; off >>= 1) s += __shfl_xor(s, off, 64);
  __shared__ double wsum[4];
  const int wave = threadIdx.x >> 6, lane = threadIdx.x & 63;
  if (lane == 0) wsum[wave] = s;
  __syncthreads();
  if (threadIdx.x == 0) {
    atomicAdd(loss, wsum[0] + wsum[1] + wsum[2] + wsum[3]);
  }
}

// ---------------- kernel 4: finalize loss ----------------------------------
__global__ void k4_final(const double* __restrict__ loss, float* __restrict__ out) {
  float m = (float)(*loss / ((double)NROWS * (double)DIM));
  out[0] = m + 0.25f * m;   // fl(cl + fl(0.25*cl)), cl == commitment loss bitwise
}

extern "C" void kernel_launch(void* const* d_in, const int* in_sizes, int n_in,
                              void* d_out, int out_size, void* d_ws, size_t ws_size,
                              hipStream_t stream) {
  const float* z  = (const float*)d_in[0];   // (B,L,D) fp32
  const float* cb = (const float*)d_in[1];   // (K,D) fp32
  float* out = (float*)d_out;                // [codes 4096][q_ste 3145728][loss 1]
  char* ws = (char*)d_ws;
  float*  zsq     = (float*)(ws + WS_ZSQ);
  float*  part_d  = (float*)(ws + WS_PARTD);
  int*    part_i  = (int*)  (ws + WS_PARTI);
  int*    codes_i = (int*)  (ws + WS_CODES);
  double* loss    = (double*)(ws + WS_LOSS);

  k0_zsq<<<NROWS / 4, 256, 0, stream>>>(z, zsq, loss);

  dim3 g1(GROUPS, ROWTILES);
  k1_argmin_gemm<<<g1, 256, 0, stream>>>(z, cb, zsq, part_d, part_i);

  k2_reduce<<<NROWS / 4, 256, 0, stream>>>(part_d, part_i, out, codes_i);

  k3_quant_loss<<<(NROWS * DIM / 4) / 256, 256, 0, stream>>>(z, cb, codes_i,
                                                             out + NROWS, loss);

  k4_final<<<1, 1, 0, stream>>>(loss, out + NROWS + (size_t)NROWS * DIM);
}

// Round 2
// 1877.274 us; speedup vs baseline: 3.4710x; 3.4710x over previous
//
#include <hip/hip_runtime.h>
#include <cfloat>
#include <cstdint>

#define NROWS  4096
#define DIM    768
#define KCODES 65536

#define TM 128
#define TC 128
#define BK 32
#define SA 40   // LDS row stride in halves: 80 B -> 16B-aligned b128, conflict-free phases

// workspace layout (bytes)
#define WS_ZSQ   0                    // 4096 f32
#define WS_KEYS  16384                // 4096 u64 (packed dist|idx)
#define WS_LOSS  (16384 + 32768)      // 1 f64

typedef _Float16 half_t;
typedef _Float16 half8 __attribute__((ext_vector_type(8)));
typedef float    f32x4 __attribute__((ext_vector_type(4)));

// ---- k0: per-row z_sq, init argmin keys, zero loss ------------------------
__global__ void k0_zsq(const float* __restrict__ z, float* __restrict__ zsq,
                       unsigned long long* __restrict__ keys, double* __restrict__ loss) {
  const int wave = threadIdx.x >> 6, lane = threadIdx.x & 63;
  const int row = blockIdx.x * 4 + wave;
  const float* zr = z + (size_t)row * DIM;
  float s = 0.f;
  #pragma unroll
  for (int i = 0; i < DIM / 64; ++i) { float v = zr[lane + i * 64]; s = fmaf(v, v, s); }
  #pragma unroll
  for (int off = 32; off; off >>= 1) s += __shfl_xor(s, off, 64);
  if (lane == 0) zsq[row] = s;
  const int gid = blockIdx.x * 256 + threadIdx.x;
  if (gid < NROWS) keys[gid] = ~0ull;
  if (gid == 0) *loss = 0.0;
}

// ---- k1: split-fp16 MFMA distance GEMM + fused argmin ---------------------
// grid (32 m-blocks, 512 n-blocks), 256 threads = 4 waves of 64x64.
__global__ __launch_bounds__(256, 2) void k1_mfma(
    const float* __restrict__ z, const float* __restrict__ cb,
    const float* __restrict__ zsq, unsigned long long* __restrict__ keys) {
  __shared__ half_t Ah[TM * SA], Al[TM * SA], Bh[TC * SA], Bl[TC * SA];
  __shared__ float lzs[TM];
  __shared__ float redD[TM][2];
  __shared__ int   redI[TM][2];

  const int tid  = threadIdx.x;
  const int row0  = blockIdx.x * TM;
  const int code0 = blockIdx.y * TC;
  const int wave = tid >> 6, lane = tid & 63;
  const int wm = wave & 1, wn = wave >> 1;       // 2x2 wave grid
  const int q = lane >> 4, l16 = lane & 15;

  if (tid < TM) lzs[tid] = zsq[row0 + tid];

  const int srow = tid >> 2;          // 0..63
  const int sko  = (tid & 3) * 8;     // 0,8,16,24

  f32x4 acc0[16], acc1[16];
  #pragma unroll
  for (int i = 0; i < 16; ++i) {
    acc0[i] = (f32x4){0.f, 0.f, 0.f, 0.f};
    acc1[i] = (f32x4){0.f, 0.f, 0.f, 0.f};
  }

  const float* zp = z  + (size_t)row0  * DIM;
  const float* bp = cb + (size_t)code0 * DIM;

  for (int kd = 0; kd < DIM; kd += BK) {
    __syncthreads();
    // stage A (128x32) and B (128x32) as fp16 hi/lo pairs
    #pragma unroll
    for (int s = 0; s < 2; ++s) {
      const int r = srow + s * 64;
      const float* srca = zp + (size_t)r * DIM + kd + sko;
      float4 v0 = *(const float4*)srca;
      float4 v1 = *(const float4*)(srca + 4);
      float a[8] = {v0.x, v0.y, v0.z, v0.w, v1.x, v1.y, v1.z, v1.w};
      half8 hi, lo;
      #pragma unroll
      for (int j = 0; j < 8; ++j) {
        half_t h = (half_t)a[j];
        hi[j] = h;
        lo[j] = (half_t)((a[j] - (float)h) * 4096.f);   // exact Sterbenz residual, scaled
      }
      *(half8*)&Ah[r * SA + sko] = hi;
      *(half8*)&Al[r * SA + sko] = lo;

      const float* srcb = bp + (size_t)r * DIM + kd + sko;
      v0 = *(const float4*)srcb; v1 = *(const float4*)(srcb + 4);
      float b[8] = {v0.x, v0.y, v0.z, v0.w, v1.x, v1.y, v1.z, v1.w};
      #pragma unroll
      for (int j = 0; j < 8; ++j) {
        float bs = b[j] * 4096.f;                        // exact pow2 scale -> fp16-normal
        half_t h = (half_t)bs;
        hi[j] = h;
        lo[j] = (half_t)((bs - (float)h) * 4096.f);
      }
      *(half8*)&Bh[r * SA + sko] = hi;
      *(half8*)&Bl[r * SA + sko] = lo;
    }
    __syncthreads();

    half8 fa_h[4], fa_l[4], fb_h[4], fb_l[4];
    #pragma unroll
    for (int t = 0; t < 4; ++t) {
      const int ar = (wm * 64 + t * 16 + l16) * SA + q * 8;
      fa_h[t] = *(const half8*)&Ah[ar];
      fa_l[t] = *(const half8*)&Al[ar];
      const int br = (wn * 64 + t * 16 + l16) * SA + q * 8;
      fb_h[t] = *(const half8*)&Bh[br];
      fb_l[t] = *(const half8*)&Bl[br];
    }
    #pragma unroll
    for (int tm = 0; tm < 4; ++tm)
      #pragma unroll
      for (int tn = 0; tn < 4; ++tn) {
        const int i = tm * 4 + tn;
        acc0[i] = __builtin_amdgcn_mfma_f32_16x16x32_f16(fa_h[tm], fb_h[tn], acc0[i], 0, 0, 0);
        acc1[i] = __builtin_amdgcn_mfma_f32_16x16x32_f16(fa_l[tm], fb_h[tn], acc1[i], 0, 0, 0);
        acc1[i] = __builtin_amdgcn_mfma_f32_16x16x32_f16(fa_h[tm], fb_l[tn], acc1[i], 0, 0, 0);
      }
  }

  // epilogue: d = fl(zsq - 2*dot), argmin with (d, idx) lexicographic order
  const float c1 = 2.44140625e-4f;    // 2^-12
  const float c2 = -4.8828125e-4f;    // -2^-11
  #pragma unroll
  for (int tm = 0; tm < 4; ++tm) {
    #pragma unroll
    for (int reg = 0; reg < 4; ++reg) {
      const int row_b = wm * 64 + tm * 16 + q * 4 + reg;   // C/D: row=(lane>>4)*4+reg
      const float zs = lzs[row_b];
      float bd = FLT_MAX; int bi = 0x7fffffff;
      #pragma unroll
      for (int tn = 0; tn < 4; ++tn) {
        const int i = tm * 4 + tn;
        float v = fmaf(c1, acc1[i][reg], acc0[i][reg]);    // ~ 2^12 * dot
        float d = fmaf(c2, v, zs);                         // fl(zs - 2*dot), single rounding
        const int ci = code0 + wn * 64 + tn * 16 + l16;    // C/D: col=lane&15
        if (d < bd || (d == bd && ci < bi)) { bd = d; bi = ci; }
      }
      #pragma unroll
      for (int off = 8; off; off >>= 1) {                  // reduce 16 lanes within quad
        float od = __shfl_xor(bd, off, 64);
        int   oi = __shfl_xor(bi, off, 64);
        if (od < bd || (od == bd && oi < bi)) { bd = od; bi = oi; }
      }
      if (l16 == 0) { redD[row_b][wn] = bd; redI[row_b][wn] = bi; }
    }
  }
  __syncthreads();
  if (tid < TM) {
    float d0 = redD[tid][0]; int i0 = redI[tid][0];
    float d1 = redD[tid][1]; int i1 = redI[tid][1];
    if (d1 < d0 || (d1 == d0 && i1 < i0)) { d0 = d1; i0 = i1; }
    // d > 0 always (zs ~ 700 >> |2 dot|) -> float bits order == value order
    unsigned long long key = ((unsigned long long)__float_as_uint(d0) << 32) | (unsigned int)i0;
    atomicMin(&keys[row0 + tid], key);
  }
}

// ---- k2: emit codes as float ----------------------------------------------
__global__ void k2_codes(const unsigned long long* __restrict__ keys,
                         float* __restrict__ out_codes) {
  const int r = blockIdx.x * 256 + threadIdx.x;
  out_codes[r] = (float)(unsigned int)(keys[r] & 0xffffffffull);
}

// ---- k3: gather + STE + loss sum ------------------------------------------
__global__ void k3_quant_loss(const float* __restrict__ z, const float* __restrict__ cb,
                              const unsigned long long* __restrict__ keys,
                              float* __restrict__ outq, double* __restrict__ loss) {
  const int gid = blockIdx.x * blockDim.x + threadIdx.x;
  const int e0 = gid * 4;
  const int row = e0 / DIM;
  const int col = e0 - row * DIM;
  const int c = (int)(unsigned int)(keys[row] & 0xffffffffull);
  const float4 zv = *(const float4*)(z + e0);
  const float4 qv = *(const float4*)(cb + (size_t)c * DIM + col);
  float d0 = qv.x - zv.x, d1 = qv.y - zv.y, d2 = qv.z - zv.z, d3 = qv.w - zv.w;
  float4 ov = { zv.x + d0, zv.y + d1, zv.z + d2, zv.w + d3 };  // fl(z + fl(q-z))
  *(float4*)(outq + e0) = ov;
  double s = (double)(d0 * d0) + (double)(d1 * d1) + (double)(d2 * d2) + (double)(d3 * d3);
  #pragma unroll
  for (int off = 32; off; off >>= 1) s += __shfl_xor(s, off, 64);
  __shared__ double wsum[4];
  const int wave = threadIdx.x >> 6, lane = threadIdx.x & 63;
  if (lane == 0) wsum[wave] = s;
  __syncthreads();
  if (threadIdx.x == 0) atomicAdd(loss, wsum[0] + wsum[1] + wsum[2] + wsum[3]);
}

// ---- k4: finalize loss -----------------------------------------------------
__global__ void k4_final(const double* __restrict__ loss, float* __restrict__ out) {
  float m = (float)(*loss / ((double)NROWS * (double)DIM));
  out[0] = m + 0.25f * m;
}

extern "C" void kernel_launch(void* const* d_in, const int* in_sizes, int n_in,
                              void* d_out, int out_size, void* d_ws, size_t ws_size,
                              hipStream_t stream) {
  const float* z  = (const float*)d_in[0];
  const float* cb = (const float*)d_in[1];
  float* out = (float*)d_out;          // [codes 4096][q_ste 3145728][loss 1]
  char* ws = (char*)d_ws;
  float*  zsq = (float*)(ws + WS_ZSQ);
  unsigned long long* keys = (unsigned long long*)(ws + WS_KEYS);
  double* loss = (double*)(ws + WS_LOSS);

  k0_zsq<<<NROWS / 4, 256, 0, stream>>>(z, zsq, keys, loss);

  dim3 g1(NROWS / TM, KCODES / TC);    // x fast: 32 m-blocks share one B-tile (L2 locality)
  k1_mfma<<<g1, 256, 0, stream>>>(z, cb, zsq, keys);

  k2_codes<<<NROWS / 256, 256, 0, stream>>>(keys, out);

  k3_quant_loss<<<(NROWS * DIM / 4) / 256, 256, 0, stream>>>(z, cb, keys, out + NROWS, loss);

  k4_final<<<1, 1, 0, stream>>>(loss, out + NROWS + (size_t)NROWS * DIM);
}

// Round 3
// 1564.123 us; speedup vs baseline: 4.1659x; 1.2002x over previous
//
#include <hip/hip_runtime.h>
#include <cfloat>
#include <cstdint>

#define NROWS  4096
#define DIM    768
#define KCODES 65536

#define TM 128
#define TC 128
#define BK 64          // preconv path K-chunk (halves)
#define SA 40          // fallback path LDS stride

// workspace layout (bytes)
#define WS_ZSQ   0                         // 4096 f32
#define WS_KEYS  16384                     // 4096 u64
#define WS_LOSS  49152                     // 1 f64
#define WS_AH    65536
#define WS_AL    (WS_AH + NROWS*DIM*2)     // 6356992
#define WS_BH    (WS_AL + NROWS*DIM*2)     // 12648448
#define WS_BL    (WS_BH + (size_t)KCODES*DIM*2)
#define WS_NEED  (WS_BL + (size_t)KCODES*DIM*2)   // ~204 MiB

typedef _Float16 half_t;
typedef _Float16 half8 __attribute__((ext_vector_type(8)));
typedef float    f32x4 __attribute__((ext_vector_type(4)));

__device__ __forceinline__ void gld16(half_t* lds, const half_t* g) {
  __builtin_amdgcn_global_load_lds(
      (const __attribute__((address_space(1))) unsigned int*)g,
      (__attribute__((address_space(3))) unsigned int*)lds, 16, 0, 0);
}

// ---- k0: per-row z_sq, init argmin keys, zero loss ------------------------
__global__ void k0_zsq(const float* __restrict__ z, float* __restrict__ zsq,
                       unsigned long long* __restrict__ keys, double* __restrict__ loss) {
  const int wave = threadIdx.x >> 6, lane = threadIdx.x & 63;
  const int row = blockIdx.x * 4 + wave;
  const float* zr = z + (size_t)row * DIM;
  float s = 0.f;
  #pragma unroll
  for (int i = 0; i < DIM / 64; ++i) { float v = zr[lane + i * 64]; s = fmaf(v, v, s); }
  #pragma unroll
  for (int off = 32; off; off >>= 1) s += __shfl_xor(s, off, 64);
  if (lane == 0) zsq[row] = s;
  const int gid = blockIdx.x * 256 + threadIdx.x;
  if (gid < NROWS) keys[gid] = ~0ull;
  if (gid == 0) *loss = 0.0;
}

// ---- k_conv: fp32 -> split fp16 (hi, lo*4096), bit-identical to in-loop ----
__global__ void k_conv(const float* __restrict__ src, half_t* __restrict__ h,
                       half_t* __restrict__ l, int n8, float prescale) {
  const int i = blockIdx.x * 256 + threadIdx.x;
  if (i >= n8) return;
  float4 v0 = ((const float4*)src)[2 * i];
  float4 v1 = ((const float4*)src)[2 * i + 1];
  float a[8] = {v0.x, v0.y, v0.z, v0.w, v1.x, v1.y, v1.z, v1.w};
  half8 hi, lo;
  #pragma unroll
  for (int j = 0; j < 8; ++j) {
    float s = a[j] * prescale;
    half_t hh = (half_t)s;
    hi[j] = hh;
    lo[j] = (half_t)((s - (float)hh) * 4096.f);
  }
  ((half8*)h)[i] = hi;
  ((half8*)l)[i] = lo;
}

// ---- k1_pre: MFMA GEMM on preconverted split-fp16, global_load_lds staging -
// grid (32 m-blocks, 512 n-blocks), 256 threads = 4 waves (2x2 of 64x64).
__global__ __launch_bounds__(256, 2) void k1_pre(
    const half_t* __restrict__ Ahg, const half_t* __restrict__ Alg,
    const half_t* __restrict__ Bhg, const half_t* __restrict__ Blg,
    const float* __restrict__ zsq, unsigned long long* __restrict__ keys) {
  __shared__ __align__(16) half_t sAh[TM * BK], sAl[TM * BK];
  __shared__ __align__(16) half_t sBh[TC * BK], sBl[TC * BK];
  __shared__ float lzs[TM];
  __shared__ float redD[TM][2];
  __shared__ int   redI[TM][2];

  const int tid = threadIdx.x;
  const int row0  = blockIdx.x * TM;
  const int code0 = blockIdx.y * TC;
  const int wave = tid >> 6, lane = tid & 63;
  const int wm = wave & 1, wn = wave >> 1;
  const int q = lane >> 4, l16 = lane & 15;

  if (tid < TM) lzs[tid] = zsq[row0 + tid];

  // staging map: lane -> (sub-row = lane>>3, slot = lane&7); slot holds k-group slot^subrow
  const int sr = lane >> 3;
  const int ss = lane & 7;
  const int gswz = ss ^ sr;            // global k-group for this lane's slot

  f32x4 acc0[16], acc1[16];
  #pragma unroll
  for (int i = 0; i < 16; ++i) {
    acc0[i] = (f32x4){0.f, 0.f, 0.f, 0.f};
    acc1[i] = (f32x4){0.f, 0.f, 0.f, 0.f};
  }

  const int rswz = l16 & 7;            // fragment-read swizzle key (r & 7)

  for (int kd = 0; kd < DIM; kd += BK) {
    __syncthreads();
    #pragma unroll
    for (int i = 0; i < 4; ++i) {
      const int r = wave * 32 + i * 8 + sr;
      const int loff = r * BK + ss * 8;
      const size_t ga = (size_t)(row0 + r) * DIM + kd + gswz * 8;
      gld16(&sAh[loff], Ahg + ga);
      gld16(&sAl[loff], Alg + ga);
      const size_t gb = (size_t)(code0 + r) * DIM + kd + gswz * 8;
      gld16(&sBh[loff], Bhg + gb);
      gld16(&sBl[loff], Blg + gb);
    }
    __syncthreads();

    #pragma unroll
    for (int s = 0; s < 2; ++s) {
      const int slot = (s * 4 + q) ^ rswz;       // physical slot of wanted k-group
      half8 fa_h[4], fa_l[4], fb_h[4], fb_l[4];
      #pragma unroll
      for (int t = 0; t < 4; ++t) {
        const int ao = (wm * 64 + t * 16 + l16) * BK + slot * 8;
        fa_h[t] = *(const half8*)&sAh[ao];
        fa_l[t] = *(const half8*)&sAl[ao];
        const int bo = (wn * 64 + t * 16 + l16) * BK + slot * 8;
        fb_h[t] = *(const half8*)&sBh[bo];
        fb_l[t] = *(const half8*)&sBl[bo];
      }
      #pragma unroll
      for (int tm = 0; tm < 4; ++tm)
        #pragma unroll
        for (int tn = 0; tn < 4; ++tn) {
          const int i = tm * 4 + tn;
          acc0[i] = __builtin_amdgcn_mfma_f32_16x16x32_f16(fa_h[tm], fb_h[tn], acc0[i], 0, 0, 0);
          acc1[i] = __builtin_amdgcn_mfma_f32_16x16x32_f16(fa_l[tm], fb_h[tn], acc1[i], 0, 0, 0);
          acc1[i] = __builtin_amdgcn_mfma_f32_16x16x32_f16(fa_h[tm], fb_l[tn], acc1[i], 0, 0, 0);
        }
    }
  }

  // epilogue: d = fl(zsq - 2*dot), lexicographic (d, idx) argmin
  const float c1 = 2.44140625e-4f;    // 2^-12
  const float c2 = -4.8828125e-4f;    // -2^-11
  #pragma unroll
  for (int tm = 0; tm < 4; ++tm) {
    #pragma unroll
    for (int reg = 0; reg < 4; ++reg) {
      const int row_b = wm * 64 + tm * 16 + q * 4 + reg;
      const float zs = lzs[row_b];
      float bd = FLT_MAX; int bi = 0x7fffffff;
      #pragma unroll
      for (int tn = 0; tn < 4; ++tn) {
        const int i = tm * 4 + tn;
        float v = fmaf(c1, acc1[i][reg], acc0[i][reg]);
        float d = fmaf(c2, v, zs);
        const int ci = code0 + wn * 64 + tn * 16 + l16;
        if (d < bd || (d == bd && ci < bi)) { bd = d; bi = ci; }
      }
      #pragma unroll
      for (int off = 8; off; off >>= 1) {
        float od = __shfl_xor(bd, off, 64);
        int   oi = __shfl_xor(bi, off, 64);
        if (od < bd || (od == bd && oi < bi)) { bd = od; bi = oi; }
      }
      if (l16 == 0) { redD[row_b][wn] = bd; redI[row_b][wn] = bi; }
    }
  }
  __syncthreads();
  if (tid < TM) {
    float d0 = redD[tid][0]; int i0 = redI[tid][0];
    float d1 = redD[tid][1]; int i1 = redI[tid][1];
    if (d1 < d0 || (d1 == d0 && i1 < i0)) { d0 = d1; i0 = i1; }
    unsigned long long key = ((unsigned long long)__float_as_uint(d0) << 32) | (unsigned int)i0;
    atomicMin(&keys[row0 + tid], key);
  }
}

// ---- k1_mfma: round-2 fallback (in-loop conversion), used if ws too small --
__global__ __launch_bounds__(256, 2) void k1_mfma(
    const float* __restrict__ z, const float* __restrict__ cb,
    const float* __restrict__ zsq, unsigned long long* __restrict__ keys) {
  __shared__ half_t Ah[TM * SA], Al[TM * SA], Bh[TC * SA], Bl[TC * SA];
  __shared__ float lzs[TM];
  __shared__ float redD[TM][2];
  __shared__ int   redI[TM][2];

  const int tid  = threadIdx.x;
  const int row0  = blockIdx.x * TM;
  const int code0 = blockIdx.y * TC;
  const int wave = tid >> 6, lane = tid & 63;
  const int wm = wave & 1, wn = wave >> 1;
  const int q = lane >> 4, l16 = lane & 15;

  if (tid < TM) lzs[tid] = zsq[row0 + tid];

  const int srow = tid >> 2;
  const int sko  = (tid & 3) * 8;

  f32x4 acc0[16], acc1[16];
  #pragma unroll
  for (int i = 0; i < 16; ++i) {
    acc0[i] = (f32x4){0.f, 0.f, 0.f, 0.f};
    acc1[i] = (f32x4){0.f, 0.f, 0.f, 0.f};
  }

  const float* zp = z  + (size_t)row0  * DIM;
  const float* bp = cb + (size_t)code0 * DIM;

  for (int kd = 0; kd < DIM; kd += 32) {
    __syncthreads();
    #pragma unroll
    for (int s = 0; s < 2; ++s) {
      const int r = srow + s * 64;
      const float* srca = zp + (size_t)r * DIM + kd + sko;
      float4 v0 = *(const float4*)srca;
      float4 v1 = *(const float4*)(srca + 4);
      float a[8] = {v0.x, v0.y, v0.z, v0.w, v1.x, v1.y, v1.z, v1.w};
      half8 hi, lo;
      #pragma unroll
      for (int j = 0; j < 8; ++j) {
        half_t h = (half_t)a[j];
        hi[j] = h;
        lo[j] = (half_t)((a[j] - (float)h) * 4096.f);
      }
      *(half8*)&Ah[r * SA + sko] = hi;
      *(half8*)&Al[r * SA + sko] = lo;

      const float* srcb = bp + (size_t)r * DIM + kd + sko;
      v0 = *(const float4*)srcb; v1 = *(const float4*)(srcb + 4);
      float b[8] = {v0.x, v0.y, v0.z, v0.w, v1.x, v1.y, v1.z, v1.w};
      #pragma unroll
      for (int j = 0; j < 8; ++j) {
        float bs = b[j] * 4096.f;
        half_t h = (half_t)bs;
        hi[j] = h;
        lo[j] = (half_t)((bs - (float)h) * 4096.f);
      }
      *(half8*)&Bh[r * SA + sko] = hi;
      *(half8*)&Bl[r * SA + sko] = lo;
    }
    __syncthreads();

    half8 fa_h[4], fa_l[4], fb_h[4], fb_l[4];
    #pragma unroll
    for (int t = 0; t < 4; ++t) {
      const int ar = (wm * 64 + t * 16 + l16) * SA + q * 8;
      fa_h[t] = *(const half8*)&Ah[ar];
      fa_l[t] = *(const half8*)&Al[ar];
      const int br = (wn * 64 + t * 16 + l16) * SA + q * 8;
      fb_h[t] = *(const half8*)&Bh[br];
      fb_l[t] = *(const half8*)&Bl[br];
    }
    #pragma unroll
    for (int tm = 0; tm < 4; ++tm)
      #pragma unroll
      for (int tn = 0; tn < 4; ++tn) {
        const int i = tm * 4 + tn;
        acc0[i] = __builtin_amdgcn_mfma_f32_16x16x32_f16(fa_h[tm], fb_h[tn], acc0[i], 0, 0, 0);
        acc1[i] = __builtin_amdgcn_mfma_f32_16x16x32_f16(fa_l[tm], fb_h[tn], acc1[i], 0, 0, 0);
        acc1[i] = __builtin_amdgcn_mfma_f32_16x16x32_f16(fa_h[tm], fb_l[tn], acc1[i], 0, 0, 0);
      }
  }

  const float c1 = 2.44140625e-4f;
  const float c2 = -4.8828125e-4f;
  #pragma unroll
  for (int tm = 0; tm < 4; ++tm) {
    #pragma unroll
    for (int reg = 0; reg < 4; ++reg) {
      const int row_b = wm * 64 + tm * 16 + q * 4 + reg;
      const float zs = lzs[row_b];
      float bd = FLT_MAX; int bi = 0x7fffffff;
      #pragma unroll
      for (int tn = 0; tn < 4; ++tn) {
        const int i = tm * 4 + tn;
        float v = fmaf(c1, acc1[i][reg], acc0[i][reg]);
        float d = fmaf(c2, v, zs);
        const int ci = code0 + wn * 64 + tn * 16 + l16;
        if (d < bd || (d == bd && ci < bi)) { bd = d; bi = ci; }
      }
      #pragma unroll
      for (int off = 8; off; off >>= 1) {
        float od = __shfl_xor(bd, off, 64);
        int   oi = __shfl_xor(bi, off, 64);
        if (od < bd || (od == bd && oi < bi)) { bd = od; bi = oi; }
      }
      if (l16 == 0) { redD[row_b][wn] = bd; redI[row_b][wn] = bi; }
    }
  }
  __syncthreads();
  if (tid < TM) {
    float d0 = redD[tid][0]; int i0 = redI[tid][0];
    float d1 = redD[tid][1]; int i1 = redI[tid][1];
    if (d1 < d0 || (d1 == d0 && i1 < i0)) { d0 = d1; i0 = i1; }
    unsigned long long key = ((unsigned long long)__float_as_uint(d0) << 32) | (unsigned int)i0;
    atomicMin(&keys[row0 + tid], key);
  }
}

// ---- k2: emit codes as float ----------------------------------------------
__global__ void k2_codes(const unsigned long long* __restrict__ keys,
                         float* __restrict__ out_codes) {
  const int r = blockIdx.x * 256 + threadIdx.x;
  out_codes[r] = (float)(unsigned int)(keys[r] & 0xffffffffull);
}

// ---- k3: gather + STE + loss sum ------------------------------------------
__global__ void k3_quant_loss(const float* __restrict__ z, const float* __restrict__ cb,
                              const unsigned long long* __restrict__ keys,
                              float* __restrict__ outq, double* __restrict__ loss) {
  const int gid = blockIdx.x * blockDim.x + threadIdx.x;
  const int e0 = gid * 4;
  const int row = e0 / DIM;
  const int col = e0 - row * DIM;
  const int c = (int)(unsigned int)(keys[row] & 0xffffffffull);
  const float4 zv = *(const float4*)(z + e0);
  const float4 qv = *(const float4*)(cb + (size_t)c * DIM + col);
  float d0 = qv.x - zv.x, d1 = qv.y - zv.y, d2 = qv.z - zv.z, d3 = qv.w - zv.w;
  float4 ov = { zv.x + d0, zv.y + d1, zv.z + d2, zv.w + d3 };
  *(float4*)(outq + e0) = ov;
  double s = (double)(d0 * d0) + (double)(d1 * d1) + (double)(d2 * d2) + (double)(d3 * d3);
  #pragma unroll
  for (int off = 32; off; off >>= 1) s += __shfl_xor(s, off, 64);
  __shared__ double wsum[4];
  const int wave = threadIdx.x >> 6, lane = threadIdx.x & 63;
  if (lane == 0) wsum[wave] = s;
  __syncthreads();
  if (threadIdx.x == 0) atomicAdd(loss, wsum[0] + wsum[1] + wsum[2] + wsum[3]);
}

// ---- k4: finalize loss -----------------------------------------------------
__global__ void k4_final(const double* __restrict__ loss, float* __restrict__ out) {
  float m = (float)(*loss / ((double)NROWS * (double)DIM));
  out[0] = m + 0.25f * m;
}

extern "C" void kernel_launch(void* const* d_in, const int* in_sizes, int n_in,
                              void* d_out, int out_size, void* d_ws, size_t ws_size,
                              hipStream_t stream) {
  const float* z  = (const float*)d_in[0];
  const float* cb = (const float*)d_in[1];
  float* out = (float*)d_out;          // [codes 4096][q_ste 3145728][loss 1]
  char* ws = (char*)d_ws;
  float*  zsq = (float*)(ws + WS_ZSQ);
  unsigned long long* keys = (unsigned long long*)(ws + WS_KEYS);
  double* loss = (double*)(ws + WS_LOSS);

  k0_zsq<<<NROWS / 4, 256, 0, stream>>>(z, zsq, keys, loss);

  dim3 g1(NROWS / TM, KCODES / TC);    // x fast: 32 m-blocks share B n-tile per XCD wavefront
  if (ws_size >= WS_NEED) {
    half_t* Ahg = (half_t*)(ws + WS_AH);
    half_t* Alg = (half_t*)(ws + WS_AL);
    half_t* Bhg = (half_t*)(ws + WS_BH);
    half_t* Blg = (half_t*)(ws + WS_BL);
    k_conv<<<(NROWS * DIM / 8 + 255) / 256, 256, 0, stream>>>(z, Ahg, Alg, NROWS * DIM / 8, 1.0f);
    k_conv<<<(KCODES * DIM / 8 + 255) / 256, 256, 0, stream>>>(cb, Bhg, Blg, KCODES * DIM / 8, 4096.0f);
    k1_pre<<<g1, 256, 0, stream>>>(Ahg, Alg, Bhg, Blg, zsq, keys);
  } else {
    k1_mfma<<<g1, 256, 0, stream>>>(z, cb, zsq, keys);
  }

  k2_codes<<<NROWS / 256, 256, 0, stream>>>(keys, out);

  k3_quant_loss<<<(NROWS * DIM / 4) / 256, 256, 0, stream>>>(z, cb, keys, out + NROWS, loss);

  k4_final<<<1, 1, 0, stream>>>(loss, out + NROWS + (size_t)NROWS * DIM);
}

// Round 4
// 1114.920 us; speedup vs baseline: 5.8444x; 1.4029x over previous
//
#include <hip/hip_runtime.h>
#include <cfloat>
#include <cstdint>

#define NROWS  4096
#define DIM    768
#define KCODES 65536

#define TM 128
#define TC 128
#define BK1 128        // stage-1 K-chunk (halves)
#define SA 40          // fallback path LDS stride
#define CAP 1024       // candidate list slots per row
#define DELTA 3.0e-4f  // guaranteed screening margin (worst-case err chain ~1.6e-4)

// workspace layout (bytes)
#define WS_ZSQ    0                          // 4096 f32
#define WS_RUNMIN 16384                      // 4096 u32
#define WS_CNT    32768                      // 4096 i32
#define WS_CODESI 49152                      // 4096 i32
#define WS_LOSS   65536                      // 1 f64
#define WS_LIST   131072                     // 4096*CAP i32 = 16 MB (fallback: keys u64)
#define WS_AH     (WS_LIST + (size_t)NROWS*CAP*4)
#define WS_BH     (WS_AH + (size_t)NROWS*DIM*2)
#define WS_NEED   (WS_BH + (size_t)KCODES*DIM*2)   // ~118 MiB

typedef _Float16 half_t;
typedef _Float16 half8 __attribute__((ext_vector_type(8)));
typedef float    f32x4 __attribute__((ext_vector_type(4)));

__device__ __forceinline__ void gld16(half_t* lds, const half_t* g) {
  __builtin_amdgcn_global_load_lds(
      (const __attribute__((address_space(1))) unsigned int*)g,
      (__attribute__((address_space(3))) unsigned int*)lds, 16, 0, 0);
}

// ---- k0: per-row z_sq, init runmin/cnt/keys, zero loss --------------------
__global__ void k0_zsq(const float* __restrict__ z, float* __restrict__ zsq,
                       unsigned int* __restrict__ runmin, int* __restrict__ cnt,
                       unsigned long long* __restrict__ keys, double* __restrict__ loss) {
  const int wave = threadIdx.x >> 6, lane = threadIdx.x & 63;
  const int row = blockIdx.x * 4 + wave;
  const float* zr = z + (size_t)row * DIM;
  float s = 0.f;
  #pragma unroll
  for (int i = 0; i < DIM / 64; ++i) { float v = zr[lane + i * 64]; s = fmaf(v, v, s); }
  #pragma unroll
  for (int off = 32; off; off >>= 1) s += __shfl_xor(s, off, 64);
  if (lane == 0) zsq[row] = s;
  const int gid = blockIdx.x * 256 + threadIdx.x;
  if (gid < NROWS) {
    runmin[gid] = 0x7f7fffffu;   // FLT_MAX bits
    cnt[gid] = 0;
    keys[gid] = ~0ull;           // fallback path
  }
  if (gid == 0) *loss = 0.0;
}

// ---- k_conv: fp32 -> fp16 hi component ------------------------------------
__global__ void k_conv(const float* __restrict__ src, half_t* __restrict__ h,
                       int n8, float prescale) {
  const int i = blockIdx.x * 256 + threadIdx.x;
  if (i >= n8) return;
  float4 v0 = ((const float4*)src)[2 * i];
  float4 v1 = ((const float4*)src)[2 * i + 1];
  float a[8] = {v0.x, v0.y, v0.z, v0.w, v1.x, v1.y, v1.z, v1.w};
  half8 hi;
  #pragma unroll
  for (int j = 0; j < 8; ++j) hi[j] = (half_t)(a[j] * prescale);
  ((half8*)h)[i] = hi;
}

// ---- k1_s1: single-pass fp16 MFMA screen + candidate collection -----------
// grid (32 m-blocks, 512 n-blocks), 256 threads = 4 waves (2x2 of 64x64).
__global__ __launch_bounds__(256, 2) void k1_s1(
    const half_t* __restrict__ Ahg, const half_t* __restrict__ Bhg,
    const float* __restrict__ zsq, unsigned int* __restrict__ runmin,
    int* __restrict__ cnt, int* __restrict__ list) {
  __shared__ __align__(16) half_t sA[TM * BK1];   // 32 KB
  __shared__ __align__(16) half_t sB[TC * BK1];   // 32 KB
  __shared__ float lzs[TM];
  __shared__ float redD[TM][2];
  __shared__ float lbound[TM];

  const int tid = threadIdx.x;
  const int row0  = blockIdx.x * TM;
  const int code0 = blockIdx.y * TC;
  const int wave = tid >> 6, lane = tid & 63;
  const int wm = wave & 1, wn = wave >> 1;
  const int q = lane >> 4, l16 = lane & 15;

  if (tid < TM) lzs[tid] = zsq[row0 + tid];

  f32x4 acc[16];
  #pragma unroll
  for (int i = 0; i < 16; ++i) acc[i] = (f32x4){0.f, 0.f, 0.f, 0.f};

  for (int kd = 0; kd < DIM; kd += BK1) {
    __syncthreads();
    // stage A,B (128 rows x 128 halves each); LDS dest == base + lane*16 by construction
    #pragma unroll
    for (int i = 0; i < 8; ++i) {
      const int sid  = i * 256 + tid;
      const int lrow = sid >> 4;
      const int kp   = sid & 15;
      const int klog = kp ^ (lrow & 7);        // XOR swizzle baked into global fetch
      const int loff = lrow * BK1 + kp * 8;
      gld16(&sA[loff], Ahg + (size_t)(row0 + lrow) * DIM + kd + klog * 8);
      gld16(&sB[loff], Bhg + (size_t)(code0 + lrow) * DIM + kd + klog * 8);
    }
    __syncthreads();

    #pragma unroll
    for (int s = 0; s < 4; ++s) {
      const int klq = s * 4 + q;               // logical k-group for this lane
      half8 fa[4], fb[4];
      #pragma unroll
      for (int t = 0; t < 4; ++t) {
        const int ar = wm * 64 + t * 16 + l16;
        fa[t] = *(const half8*)&sA[ar * BK1 + (klq ^ (ar & 7)) * 8];
        const int br = wn * 64 + t * 16 + l16;
        fb[t] = *(const half8*)&sB[br * BK1 + (klq ^ (br & 7)) * 8];
      }
      #pragma unroll
      for (int tm = 0; tm < 4; ++tm)
        #pragma unroll
        for (int tn = 0; tn < 4; ++tn)
          acc[tm * 4 + tn] = __builtin_amdgcn_mfma_f32_16x16x32_f16(fa[tm], fb[tn], acc[tm * 4 + tn], 0, 0, 0);
    }
  }

  // transform acc -> approx distance d~ = fl(zs - 2^-11 * acc)
  const float c2 = -4.8828125e-4f;   // -2^-11 (B prescaled by 4096)
  #pragma unroll
  for (int tm = 0; tm < 4; ++tm)
    #pragma unroll
    for (int reg = 0; reg < 4; ++reg) {
      const float zs = lzs[wm * 64 + tm * 16 + q * 4 + reg];
      #pragma unroll
      for (int tn = 0; tn < 4; ++tn)
        acc[tm * 4 + tn][reg] = fmaf(c2, acc[tm * 4 + tn][reg], zs);
    }

  // block-local per-row min
  #pragma unroll
  for (int tm = 0; tm < 4; ++tm)
    #pragma unroll
    for (int reg = 0; reg < 4; ++reg) {
      float m = acc[tm * 4 + 0][reg];
      #pragma unroll
      for (int tn = 1; tn < 4; ++tn) m = fminf(m, acc[tm * 4 + tn][reg]);
      #pragma unroll
      for (int off = 8; off; off >>= 1) m = fminf(m, __shfl_xor(m, off, 64));
      if (l16 == 0) redD[wm * 64 + tm * 16 + q * 4 + reg][wn] = m;
    }
  __syncthreads();
  if (tid < TM) {
    const float lm = fminf(redD[tid][0], redD[tid][1]);
    const unsigned rg = runmin[row0 + tid];          // stale-safe: always >= true min
    atomicMin(&runmin[row0 + tid], __float_as_uint(lm));
    lbound[tid] = fminf(lm, __uint_as_float(rg)) + DELTA;
  }
  __syncthreads();

  // collect candidates within margin (provably includes reference winner + ties)
  #pragma unroll
  for (int tm = 0; tm < 4; ++tm)
    #pragma unroll
    for (int reg = 0; reg < 4; ++reg) {
      const int row_b = wm * 64 + tm * 16 + q * 4 + reg;
      const float b = lbound[row_b];
      #pragma unroll
      for (int tn = 0; tn < 4; ++tn) {
        const float d = acc[tm * 4 + tn][reg];
        if (d <= b) {
          const int grow = row0 + row_b;
          const int pos = atomicAdd(&cnt[grow], 1);
          if (pos < CAP) list[(size_t)grow * CAP + pos] = code0 + wn * 64 + tn * 16 + l16;
        }
      }
    }
}

// ---- k_refine: exact fp64 re-score of survivors, emit codes ---------------
__global__ void k_refine(const float* __restrict__ z, const float* __restrict__ cb,
                         const float* __restrict__ zsq, const int* __restrict__ cnt,
                         const int* __restrict__ list, float* __restrict__ out_codes,
                         int* __restrict__ codes_i) {
  const int r = blockIdx.x;
  const int wave = threadIdx.x >> 6, lane = threadIdx.x & 63;
  __shared__ unsigned long long wbest[4];
  int n = cnt[r]; if (n > CAP) n = CAP;
  const bool empty = (n == 0); if (empty) n = 1;
  unsigned long long best = ~0ull;
  const float* zr = z + (size_t)r * DIM;
  for (int ci = wave; ci < n; ci += 4) {
    const int idx = empty ? 0 : list[(size_t)r * CAP + ci];
    const float* cr = cb + (size_t)idx * DIM;
    double s = 0.0;
    #pragma unroll
    for (int j = 0; j < 12; ++j) {
      const int k = lane + j * 64;
      s += (double)zr[k] * (double)cr[k];
    }
    #pragma unroll
    for (int off = 32; off; off >>= 1) s += __shfl_xor(s, off, 64);
    const float d = (float)((double)zsq[r] - 2.0 * s);   // single rounding, ref semantics
    const unsigned long long key =
        ((unsigned long long)__float_as_uint(d) << 32) | (unsigned)idx;
    if (key < best) best = key;                          // (d, idx) lexicographic
  }
  if (lane == 0) wbest[wave] = best;
  __syncthreads();
  if (threadIdx.x == 0) {
    unsigned long long b = wbest[0];
    #pragma unroll
    for (int w = 1; w < 4; ++w) if (wbest[w] < b) b = wbest[w];
    const int idx = (int)(unsigned)(b & 0xffffffffull);
    codes_i[r] = idx;
    out_codes[r] = (float)idx;
  }
}

// ---- k1_mfma: round-2 fallback (3-pass, inline conversion) ----------------
__global__ __launch_bounds__(256, 2) void k1_mfma(
    const float* __restrict__ z, const float* __restrict__ cb,
    const float* __restrict__ zsq, unsigned long long* __restrict__ keys) {
  __shared__ half_t Ah[TM * SA], Al[TM * SA], Bh[TC * SA], Bl[TC * SA];
  __shared__ float lzs[TM];
  __shared__ float redD[TM][2];
  __shared__ int   redI[TM][2];

  const int tid  = threadIdx.x;
  const int row0  = blockIdx.x * TM;
  const int code0 = blockIdx.y * TC;
  const int wave = tid >> 6, lane = tid & 63;
  const int wm = wave & 1, wn = wave >> 1;
  const int q = lane >> 4, l16 = lane & 15;

  if (tid < TM) lzs[tid] = zsq[row0 + tid];

  const int srow = tid >> 2;
  const int sko  = (tid & 3) * 8;

  f32x4 acc0[16], acc1[16];
  #pragma unroll
  for (int i = 0; i < 16; ++i) {
    acc0[i] = (f32x4){0.f, 0.f, 0.f, 0.f};
    acc1[i] = (f32x4){0.f, 0.f, 0.f, 0.f};
  }

  const float* zp = z  + (size_t)row0  * DIM;
  const float* bp = cb + (size_t)code0 * DIM;

  for (int kd = 0; kd < DIM; kd += 32) {
    __syncthreads();
    #pragma unroll
    for (int s = 0; s < 2; ++s) {
      const int r = srow + s * 64;
      const float* srca = zp + (size_t)r * DIM + kd + sko;
      float4 v0 = *(const float4*)srca;
      float4 v1 = *(const float4*)(srca + 4);
      float a[8] = {v0.x, v0.y, v0.z, v0.w, v1.x, v1.y, v1.z, v1.w};
      half8 hi, lo;
      #pragma unroll
      for (int j = 0; j < 8; ++j) {
        half_t h = (half_t)a[j];
        hi[j] = h;
        lo[j] = (half_t)((a[j] - (float)h) * 4096.f);
      }
      *(half8*)&Ah[r * SA + sko] = hi;
      *(half8*)&Al[r * SA + sko] = lo;
      const float* srcb = bp + (size_t)r * DIM + kd + sko;
      v0 = *(const float4*)srcb; v1 = *(const float4*)(srcb + 4);
      float b[8] = {v0.x, v0.y, v0.z, v0.w, v1.x, v1.y, v1.z, v1.w};
      #pragma unroll
      for (int j = 0; j < 8; ++j) {
        float bs = b[j] * 4096.f;
        half_t h = (half_t)bs;
        hi[j] = h;
        lo[j] = (half_t)((bs - (float)h) * 4096.f);
      }
      *(half8*)&Bh[r * SA + sko] = hi;
      *(half8*)&Bl[r * SA + sko] = lo;
    }
    __syncthreads();

    half8 fa_h[4], fa_l[4], fb_h[4], fb_l[4];
    #pragma unroll
    for (int t = 0; t < 4; ++t) {
      const int ar = (wm * 64 + t * 16 + l16) * SA + q * 8;
      fa_h[t] = *(const half8*)&Ah[ar];
      fa_l[t] = *(const half8*)&Al[ar];
      const int br = (wn * 64 + t * 16 + l16) * SA + q * 8;
      fb_h[t] = *(const half8*)&Bh[br];
      fb_l[t] = *(const half8*)&Bl[br];
    }
    #pragma unroll
    for (int tm = 0; tm < 4; ++tm)
      #pragma unroll
      for (int tn = 0; tn < 4; ++tn) {
        const int i = tm * 4 + tn;
        acc0[i] = __builtin_amdgcn_mfma_f32_16x16x32_f16(fa_h[tm], fb_h[tn], acc0[i], 0, 0, 0);
        acc1[i] = __builtin_amdgcn_mfma_f32_16x16x32_f16(fa_l[tm], fb_h[tn], acc1[i], 0, 0, 0);
        acc1[i] = __builtin_amdgcn_mfma_f32_16x16x32_f16(fa_h[tm], fb_l[tn], acc1[i], 0, 0, 0);
      }
  }

  const float c1 = 2.44140625e-4f;
  const float c2 = -4.8828125e-4f;
  #pragma unroll
  for (int tm = 0; tm < 4; ++tm) {
    #pragma unroll
    for (int reg = 0; reg < 4; ++reg) {
      const int row_b = wm * 64 + tm * 16 + q * 4 + reg;
      const float zs = lzs[row_b];
      float bd = FLT_MAX; int bi = 0x7fffffff;
      #pragma unroll
      for (int tn = 0; tn < 4; ++tn) {
        const int i = tm * 4 + tn;
        float v = fmaf(c1, acc1[i][reg], acc0[i][reg]);
        float d = fmaf(c2, v, zs);
        const int ci = code0 + wn * 64 + tn * 16 + l16;
        if (d < bd || (d == bd && ci < bi)) { bd = d; bi = ci; }
      }
      #pragma unroll
      for (int off = 8; off; off >>= 1) {
        float od = __shfl_xor(bd, off, 64);
        int   oi = __shfl_xor(bi, off, 64);
        if (od < bd || (od == bd && oi < bi)) { bd = od; bi = oi; }
      }
      if (l16 == 0) { redD[row_b][wn] = bd; redI[row_b][wn] = bi; }
    }
  }
  __syncthreads();
  if (tid < TM) {
    float d0 = redD[tid][0]; int i0 = redI[tid][0];
    float d1 = redD[tid][1]; int i1 = redI[tid][1];
    if (d1 < d0 || (d1 == d0 && i1 < i0)) { d0 = d1; i0 = i1; }
    unsigned long long key = ((unsigned long long)__float_as_uint(d0) << 32) | (unsigned int)i0;
    atomicMin(&keys[row0 + tid], key);
  }
}

// ---- k2: fallback code emit -----------------------------------------------
__global__ void k2_codes(const unsigned long long* __restrict__ keys,
                         float* __restrict__ out_codes, int* __restrict__ codes_i) {
  const int r = blockIdx.x * 256 + threadIdx.x;
  const int idx = (int)(unsigned int)(keys[r] & 0xffffffffull);
  out_codes[r] = (float)idx;
  codes_i[r] = idx;
}

// ---- k3: gather + STE + loss sum ------------------------------------------
__global__ void k3_quant_loss(const float* __restrict__ z, const float* __restrict__ cb,
                              const int* __restrict__ codes, float* __restrict__ outq,
                              double* __restrict__ loss) {
  const int gid = blockIdx.x * blockDim.x + threadIdx.x;
  const int e0 = gid * 4;
  const int row = e0 / DIM;
  const int col = e0 - row * DIM;
  const int c = codes[row];
  const float4 zv = *(const float4*)(z + e0);
  const float4 qv = *(const float4*)(cb + (size_t)c * DIM + col);
  float d0 = qv.x - zv.x, d1 = qv.y - zv.y, d2 = qv.z - zv.z, d3 = qv.w - zv.w;
  float4 ov = { zv.x + d0, zv.y + d1, zv.z + d2, zv.w + d3 };
  *(float4*)(outq + e0) = ov;
  double s = (double)(d0 * d0) + (double)(d1 * d1) + (double)(d2 * d2) + (double)(d3 * d3);
  #pragma unroll
  for (int off = 32; off; off >>= 1) s += __shfl_xor(s, off, 64);
  __shared__ double wsum[4];
  const int wave = threadIdx.x >> 6, lane = threadIdx.x & 63;
  if (lane == 0) wsum[wave] = s;
  __syncthreads();
  if (threadIdx.x == 0) atomicAdd(loss, wsum[0] + wsum[1] + wsum[2] + wsum[3]);
}

// ---- k4: finalize loss -----------------------------------------------------
__global__ void k4_final(const double* __restrict__ loss, float* __restrict__ out) {
  float m = (float)(*loss / ((double)NROWS * (double)DIM));
  out[0] = m + 0.25f * m;
}

extern "C" void kernel_launch(void* const* d_in, const int* in_sizes, int n_in,
                              void* d_out, int out_size, void* d_ws, size_t ws_size,
                              hipStream_t stream) {
  const float* z  = (const float*)d_in[0];
  const float* cb = (const float*)d_in[1];
  float* out = (float*)d_out;          // [codes 4096][q_ste 3145728][loss 1]
  char* ws = (char*)d_ws;
  float*  zsq = (float*)(ws + WS_ZSQ);
  unsigned int* runmin = (unsigned int*)(ws + WS_RUNMIN);
  int* cnt     = (int*)(ws + WS_CNT);
  int* codes_i = (int*)(ws + WS_CODESI);
  double* loss = (double*)(ws + WS_LOSS);
  int* list    = (int*)(ws + WS_LIST);
  unsigned long long* keys = (unsigned long long*)(ws + WS_LIST);

  k0_zsq<<<NROWS / 4, 256, 0, stream>>>(z, zsq, runmin, cnt, keys, loss);

  dim3 g1(NROWS / TM, KCODES / TC);    // m fast: concurrent blocks share B n-slice
  if (ws_size >= WS_NEED) {
    half_t* Ahg = (half_t*)(ws + WS_AH);
    half_t* Bhg = (half_t*)(ws + WS_BH);
    k_conv<<<(NROWS * DIM / 8 + 255) / 256, 256, 0, stream>>>(z, Ahg, NROWS * DIM / 8, 1.0f);
    k_conv<<<(KCODES * DIM / 8 + 255) / 256, 256, 0, stream>>>(cb, Bhg, KCODES * DIM / 8, 4096.0f);
    k1_s1<<<g1, 256, 0, stream>>>(Ahg, Bhg, zsq, runmin, cnt, list);
    k_refine<<<NROWS, 256, 0, stream>>>(z, cb, zsq, cnt, list, out, codes_i);
  } else {
    k1_mfma<<<g1, 256, 0, stream>>>(z, cb, zsq, keys);
    k2_codes<<<NROWS / 256, 256, 0, stream>>>(keys, out, codes_i);
  }

  k3_quant_loss<<<(NROWS * DIM / 4) / 256, 256, 0, stream>>>(z, cb, codes_i, out + NROWS, loss);

  k4_final<<<1, 1, 0, stream>>>(loss, out + NROWS + (size_t)NROWS * DIM);
}

// Round 5
// 928.103 us; speedup vs baseline: 7.0208x; 1.2013x over previous
//
#include <hip/hip_runtime.h>
#include <cfloat>
#include <cstdint>

#define NROWS  4096
#define DIM    768
#define KCODES 65536

#define TM 128
#define TC 128
#define BK 64          // stage-1 K-chunk (halves); 128-B LDS row stride (verified r3 geometry)
#define SA 40          // fallback path LDS stride
#define CAP 2048       // candidate list slots per row
#define DELTA 3.0e-4f  // guaranteed screening margin (worst-case err chain ~1.6e-4)

// workspace layout (bytes)
#define WS_ZSQ    0                          // 4096 f32
#define WS_RUNMIN 16384                      // 4096 u32
#define WS_CNT    32768                      // 4096 i32
#define WS_CODESI 49152                      // 4096 i32 (fallback)
#define WS_LOSS   65536                      // 1 f64
#define WS_LIST   131072                     // 4096*CAP i32 = 32 MB (fallback: keys u64)
#define WS_AH     (WS_LIST + (size_t)NROWS*CAP*4)
#define WS_BH     (WS_AH + (size_t)NROWS*DIM*2)
#define WS_NEED   (WS_BH + (size_t)KCODES*DIM*2)   // ~135 MiB (ws proven >= 204 MiB in r3)

typedef _Float16 half_t;
typedef _Float16 half4 __attribute__((ext_vector_type(4)));
typedef _Float16 half8 __attribute__((ext_vector_type(8)));
typedef float    f32x4 __attribute__((ext_vector_type(4)));

__device__ __forceinline__ void gld16(half_t* lds, const half_t* g) {
  __builtin_amdgcn_global_load_lds(
      (const __attribute__((address_space(1))) unsigned int*)g,
      (__attribute__((address_space(3))) unsigned int*)lds, 16, 0, 0);
}

// ---- k_convA: z -> fp16 hi, z_sq per row, init runmin/cnt, zero loss ------
// grid 1024 x 256; one row per wave; lane handles 3 float4 (12 elems).
__global__ void k_convA(const float* __restrict__ z, half_t* __restrict__ h,
                        float* __restrict__ zsq, unsigned int* __restrict__ runmin,
                        int* __restrict__ cnt, double* __restrict__ loss) {
  const int wave = threadIdx.x >> 6, lane = threadIdx.x & 63;
  const int row = blockIdx.x * 4 + wave;
  const float4* zr = (const float4*)(z + (size_t)row * DIM);
  half_t* hr = h + (size_t)row * DIM;
  float s = 0.f;
  #pragma unroll
  for (int p = 0; p < 3; ++p) {
    float4 v = zr[lane + p * 64];
    s = fmaf(v.x, v.x, s); s = fmaf(v.y, v.y, s);
    s = fmaf(v.z, v.z, s); s = fmaf(v.w, v.w, s);
    half4 hv = { (half_t)v.x, (half_t)v.y, (half_t)v.z, (half_t)v.w };
    *(half4*)(hr + (lane + p * 64) * 4) = hv;
  }
  #pragma unroll
  for (int off = 32; off; off >>= 1) s += __shfl_xor(s, off, 64);
  if (lane == 0) zsq[row] = s;
  const int gid = blockIdx.x * 256 + threadIdx.x;
  if (gid < NROWS) { runmin[gid] = 0x7f7fffffu; cnt[gid] = 0; }
  if (gid == 0) *loss = 0.0;
}

// ---- k_convB: cb -> fp16 hi, prescaled by 4096 ----------------------------
__global__ void k_convB(const float* __restrict__ src, half_t* __restrict__ h, int n8) {
  const int i = blockIdx.x * 256 + threadIdx.x;
  if (i >= n8) return;
  float4 v0 = ((const float4*)src)[2 * i];
  float4 v1 = ((const float4*)src)[2 * i + 1];
  float a[8] = {v0.x, v0.y, v0.z, v0.w, v1.x, v1.y, v1.z, v1.w};
  half8 hi;
  #pragma unroll
  for (int j = 0; j < 8; ++j) hi[j] = (half_t)(a[j] * 4096.f);
  ((half8*)h)[i] = hi;
}

// ---- k1_s1: single-pass fp16 MFMA screen + candidate collection -----------
// grid (32 m-blocks, 512 n-blocks), 256 threads = 4 waves (2x2 of 64x64).
// BK=64 / 128-B stride geometry (round-3 verified, ~0 conflicts); 4 blocks/CU.
__global__ __launch_bounds__(256, 4) void k1_s1(
    const half_t* __restrict__ Ahg, const half_t* __restrict__ Bhg,
    const float* __restrict__ zsq, unsigned int* __restrict__ runmin,
    int* __restrict__ cnt, int* __restrict__ list) {
  __shared__ __align__(16) half_t sA[TM * BK];   // 16 KB
  __shared__ __align__(16) half_t sB[TC * BK];   // 16 KB
  __shared__ float lzs[TM];
  __shared__ float redD[TM][2];
  __shared__ float lbound[TM];

  const int tid = threadIdx.x;
  const int row0  = blockIdx.x * TM;
  const int code0 = blockIdx.y * TC;
  const int wave = tid >> 6, lane = tid & 63;
  const int wm = wave & 1, wn = wave >> 1;
  const int q = lane >> 4, l16 = lane & 15;

  if (tid < TM) lzs[tid] = zsq[row0 + tid];

  // staging map (r3-verified): lane -> (sub-row = lane>>3, slot = lane&7)
  const int sr = lane >> 3;
  const int ss = lane & 7;
  const int gswz = ss ^ sr;            // logical k-group fetched into physical slot ss

  f32x4 acc[16];
  #pragma unroll
  for (int i = 0; i < 16; ++i) acc[i] = (f32x4){0.f, 0.f, 0.f, 0.f};

  for (int kd = 0; kd < DIM; kd += BK) {
    __syncthreads();
    #pragma unroll
    for (int i = 0; i < 4; ++i) {
      const int r = wave * 32 + i * 8 + sr;
      const int loff = r * BK + ss * 8;          // = wave-base + lane*16 B (contiguous)
      gld16(&sA[loff], Ahg + (size_t)(row0  + r) * DIM + kd + gswz * 8);
      gld16(&sB[loff], Bhg + (size_t)(code0 + r) * DIM + kd + gswz * 8);
    }
    __syncthreads();

    #pragma unroll
    for (int s = 0; s < 2; ++s) {
      const int klq = s * 4 + q;                 // logical k-group
      half8 fa[4], fb[4];
      #pragma unroll
      for (int t = 0; t < 4; ++t) {
        const int ar = wm * 64 + t * 16 + l16;
        fa[t] = *(const half8*)&sA[ar * BK + ((klq ^ (ar & 7)) * 8)];
        const int br = wn * 64 + t * 16 + l16;
        fb[t] = *(const half8*)&sB[br * BK + ((klq ^ (br & 7)) * 8)];
      }
      #pragma unroll
      for (int tm = 0; tm < 4; ++tm)
        #pragma unroll
        for (int tn = 0; tn < 4; ++tn)
          acc[tm * 4 + tn] = __builtin_amdgcn_mfma_f32_16x16x32_f16(fa[tm], fb[tn], acc[tm * 4 + tn], 0, 0, 0);
    }
  }

  // transform acc -> approx distance d~ = fl(zs - 2^-11 * acc)
  const float c2 = -4.8828125e-4f;   // -2^-11 (B prescaled by 4096)
  #pragma unroll
  for (int tm = 0; tm < 4; ++tm)
    #pragma unroll
    for (int reg = 0; reg < 4; ++reg) {
      const float zs = lzs[wm * 64 + tm * 16 + q * 4 + reg];
      #pragma unroll
      for (int tn = 0; tn < 4; ++tn)
        acc[tm * 4 + tn][reg] = fmaf(c2, acc[tm * 4 + tn][reg], zs);
    }

  // block-local per-row min
  #pragma unroll
  for (int tm = 0; tm < 4; ++tm)
    #pragma unroll
    for (int reg = 0; reg < 4; ++reg) {
      float m = acc[tm * 4 + 0][reg];
      #pragma unroll
      for (int tn = 1; tn < 4; ++tn) m = fminf(m, acc[tm * 4 + tn][reg]);
      #pragma unroll
      for (int off = 8; off; off >>= 1) m = fminf(m, __shfl_xor(m, off, 64));
      if (l16 == 0) redD[wm * 64 + tm * 16 + q * 4 + reg][wn] = m;
    }
  __syncthreads();
  if (tid < TM) {
    const float lm = fminf(redD[tid][0], redD[tid][1]);
    const unsigned rg = runmin[row0 + tid];          // stale-safe: always >= true min
    atomicMin(&runmin[row0 + tid], __float_as_uint(lm));
    lbound[tid] = fminf(lm, __uint_as_float(rg)) + DELTA;
  }
  __syncthreads();

  // collect candidates within margin (provably includes reference winner + ties)
  #pragma unroll
  for (int tm = 0; tm < 4; ++tm)
    #pragma unroll
    for (int reg = 0; reg < 4; ++reg) {
      const int row_b = wm * 64 + tm * 16 + q * 4 + reg;
      const float b = lbound[row_b];
      #pragma unroll
      for (int tn = 0; tn < 4; ++tn) {
        const float d = acc[tm * 4 + tn][reg];
        if (d <= b) {
          const int grow = row0 + row_b;
          const int pos = atomicAdd(&cnt[grow], 1);
          if (pos < CAP) list[(size_t)grow * CAP + pos] = code0 + wn * 64 + tn * 16 + l16;
        }
      }
    }
}

// ---- k_refine: fp64 re-score of survivors + gather + STE + loss (fused) ---
// one row per block, 256 threads.
__global__ void k_refine(const float* __restrict__ z, const float* __restrict__ cb,
                         const float* __restrict__ zsq, const int* __restrict__ cnt,
                         const int* __restrict__ list, float* __restrict__ out_codes,
                         float* __restrict__ outq, double* __restrict__ loss) {
  const int r = blockIdx.x;
  const int tid = threadIdx.x, wave = tid >> 6, lane = tid & 63;
  __shared__ unsigned long long wbest[4];
  __shared__ double wsum[4];
  __shared__ int sidx;
  __shared__ __align__(16) float zsh[DIM];

  if (tid < DIM / 4) ((float4*)zsh)[tid] = ((const float4*)(z + (size_t)r * DIM))[tid];
  __syncthreads();

  int n = cnt[r]; if (n > CAP) n = CAP;
  const bool empty = (n == 0); if (empty) n = 1;   // winner provably collected; guard anyway
  const double zsd = (double)zsq[r];
  unsigned long long best = ~0ull;
  for (int ci = wave; ci < n; ci += 4) {
    const int idx = empty ? 0 : list[(size_t)r * CAP + ci];
    const float4* cr = (const float4*)(cb + (size_t)idx * DIM);
    double s = 0.0;
    #pragma unroll
    for (int p = 0; p < 3; ++p) {
      const float4 cv = cr[lane + p * 64];
      const float4 zv = ((const float4*)zsh)[lane + p * 64];
      s += (double)zv.x * cv.x + (double)zv.y * cv.y +
           (double)zv.z * cv.z + (double)zv.w * cv.w;
    }
    #pragma unroll
    for (int off = 32; off; off >>= 1) s += __shfl_xor(s, off, 64);
    const float d = (float)(zsd - 2.0 * s);        // single rounding, ref semantics
    const unsigned long long key =
        ((unsigned long long)__float_as_uint(d) << 32) | (unsigned)idx;
    if (key < best) best = key;                    // (d, idx) lexicographic
  }
  if (lane == 0) wbest[wave] = best;
  __syncthreads();
  if (tid == 0) {
    unsigned long long b = wbest[0];
    #pragma unroll
    for (int w = 1; w < 4; ++w) if (wbest[w] < b) b = wbest[w];
    const int idx = (int)(unsigned)(b & 0xffffffffull);
    sidx = idx;
    out_codes[r] = (float)idx;
  }
  __syncthreads();

  // gather + STE + loss partial for this row
  const int c = sidx;
  double ls = 0.0;
  #pragma unroll
  for (int j = 0; j < 3; ++j) {
    const int e = tid + j * 256;
    const float qx = cb[(size_t)c * DIM + e];
    const float zx = zsh[e];
    const float dd = qx - zx;
    outq[(size_t)r * DIM + e] = zx + dd;           // fl(z + fl(q-z)) bitwise
    ls += (double)dd * (double)dd;
  }
  #pragma unroll
  for (int off = 32; off; off >>= 1) ls += __shfl_xor(ls, off, 64);
  if (lane == 0) wsum[wave] = ls;
  __syncthreads();
  if (tid == 0) atomicAdd(loss, wsum[0] + wsum[1] + wsum[2] + wsum[3]);
}

// ---- k4: finalize loss -----------------------------------------------------
__global__ void k4_final(const double* __restrict__ loss, float* __restrict__ out) {
  float m = (float)(*loss / ((double)NROWS * (double)DIM));
  out[0] = m + 0.25f * m;
}

// ======================= fallback path (ws too small) =======================
__global__ void k0_zsq(const float* __restrict__ z, float* __restrict__ zsq,
                       unsigned long long* __restrict__ keys, double* __restrict__ loss) {
  const int wave = threadIdx.x >> 6, lane = threadIdx.x & 63;
  const int row = blockIdx.x * 4 + wave;
  const float* zr = z + (size_t)row * DIM;
  float s = 0.f;
  #pragma unroll
  for (int i = 0; i < DIM / 64; ++i) { float v = zr[lane + i * 64]; s = fmaf(v, v, s); }
  #pragma unroll
  for (int off = 32; off; off >>= 1) s += __shfl_xor(s, off, 64);
  if (lane == 0) zsq[row] = s;
  const int gid = blockIdx.x * 256 + threadIdx.x;
  if (gid < NROWS) keys[gid] = ~0ull;
  if (gid == 0) *loss = 0.0;
}

__global__ __launch_bounds__(256, 2) void k1_mfma(
    const float* __restrict__ z, const float* __restrict__ cb,
    const float* __restrict__ zsq, unsigned long long* __restrict__ keys) {
  __shared__ half_t Ah[TM * SA], Al[TM * SA], Bh[TC * SA], Bl[TC * SA];
  __shared__ float lzs[TM];
  __shared__ float redD[TM][2];
  __shared__ int   redI[TM][2];

  const int tid  = threadIdx.x;
  const int row0  = blockIdx.x * TM;
  const int code0 = blockIdx.y * TC;
  const int wave = tid >> 6, lane = tid & 63;
  const int wm = wave & 1, wn = wave >> 1;
  const int q = lane >> 4, l16 = lane & 15;

  if (tid < TM) lzs[tid] = zsq[row0 + tid];

  const int srow = tid >> 2;
  const int sko  = (tid & 3) * 8;

  f32x4 acc0[16], acc1[16];
  #pragma unroll
  for (int i = 0; i < 16; ++i) {
    acc0[i] = (f32x4){0.f, 0.f, 0.f, 0.f};
    acc1[i] = (f32x4){0.f, 0.f, 0.f, 0.f};
  }

  const float* zp = z  + (size_t)row0  * DIM;
  const float* bp = cb + (size_t)code0 * DIM;

  for (int kd = 0; kd < DIM; kd += 32) {
    __syncthreads();
    #pragma unroll
    for (int s = 0; s < 2; ++s) {
      const int r = srow + s * 64;
      const float* srca = zp + (size_t)r * DIM + kd + sko;
      float4 v0 = *(const float4*)srca;
      float4 v1 = *(const float4*)(srca + 4);
      float a[8] = {v0.x, v0.y, v0.z, v0.w, v1.x, v1.y, v1.z, v1.w};
      half8 hi, lo;
      #pragma unroll
      for (int j = 0; j < 8; ++j) {
        half_t h = (half_t)a[j];
        hi[j] = h;
        lo[j] = (half_t)((a[j] - (float)h) * 4096.f);
      }
      *(half8*)&Ah[r * SA + sko] = hi;
      *(half8*)&Al[r * SA + sko] = lo;
      const float* srcb = bp + (size_t)r * DIM + kd + sko;
      v0 = *(const float4*)srcb; v1 = *(const float4*)(srcb + 4);
      float b[8] = {v0.x, v0.y, v0.z, v0.w, v1.x, v1.y, v1.z, v1.w};
      #pragma unroll
      for (int j = 0; j < 8; ++j) {
        float bs = b[j] * 4096.f;
        half_t h = (half_t)bs;
        hi[j] = h;
        lo[j] = (half_t)((bs - (float)h) * 4096.f);
      }
      *(half8*)&Bh[r * SA + sko] = hi;
      *(half8*)&Bl[r * SA + sko] = lo;
    }
    __syncthreads();

    half8 fa_h[4], fa_l[4], fb_h[4], fb_l[4];
    #pragma unroll
    for (int t = 0; t < 4; ++t) {
      const int ar = (wm * 64 + t * 16 + l16) * SA + q * 8;
      fa_h[t] = *(const half8*)&Ah[ar];
      fa_l[t] = *(const half8*)&Al[ar];
      const int br = (wn * 64 + t * 16 + l16) * SA + q * 8;
      fb_h[t] = *(const half8*)&Bh[br];
      fb_l[t] = *(const half8*)&Bl[br];
    }
    #pragma unroll
    for (int tm = 0; tm < 4; ++tm)
      #pragma unroll
      for (int tn = 0; tn < 4; ++tn) {
        const int i = tm * 4 + tn;
        acc0[i] = __builtin_amdgcn_mfma_f32_16x16x32_f16(fa_h[tm], fb_h[tn], acc0[i], 0, 0, 0);
        acc1[i] = __builtin_amdgcn_mfma_f32_16x16x32_f16(fa_l[tm], fb_h[tn], acc1[i], 0, 0, 0);
        acc1[i] = __builtin_amdgcn_mfma_f32_16x16x32_f16(fa_h[tm], fb_l[tn], acc1[i], 0, 0, 0);
      }
  }

  const float c1 = 2.44140625e-4f;
  const float c2 = -4.8828125e-4f;
  #pragma unroll
  for (int tm = 0; tm < 4; ++tm) {
    #pragma unroll
    for (int reg = 0; reg < 4; ++reg) {
      const int row_b = wm * 64 + tm * 16 + q * 4 + reg;
      const float zs = lzs[row_b];
      float bd = FLT_MAX; int bi = 0x7fffffff;
      #pragma unroll
      for (int tn = 0; tn < 4; ++tn) {
        const int i = tm * 4 + tn;
        float v = fmaf(c1, acc1[i][reg], acc0[i][reg]);
        float d = fmaf(c2, v, zs);
        const int ci = code0 + wn * 64 + tn * 16 + l16;
        if (d < bd || (d == bd && ci < bi)) { bd = d; bi = ci; }
      }
      #pragma unroll
      for (int off = 8; off; off >>= 1) {
        float od = __shfl_xor(bd, off, 64);
        int   oi = __shfl_xor(bi, off, 64);
        if (od < bd || (od == bd && oi < bi)) { bd = od; bi = oi; }
      }
      if (l16 == 0) { redD[row_b][wn] = bd; redI[row_b][wn] = bi; }
    }
  }
  __syncthreads();
  if (tid < TM) {
    float d0 = redD[tid][0]; int i0 = redI[tid][0];
    float d1 = redD[tid][1]; int i1 = redI[tid][1];
    if (d1 < d0 || (d1 == d0 && i1 < i0)) { d0 = d1; i0 = i1; }
    unsigned long long key = ((unsigned long long)__float_as_uint(d0) << 32) | (unsigned int)i0;
    atomicMin(&keys[row0 + tid], key);
  }
}

__global__ void k2_codes(const unsigned long long* __restrict__ keys,
                         float* __restrict__ out_codes, int* __restrict__ codes_i) {
  const int r = blockIdx.x * 256 + threadIdx.x;
  const int idx = (int)(unsigned int)(keys[r] & 0xffffffffull);
  out_codes[r] = (float)idx;
  codes_i[r] = idx;
}

__global__ void k3_quant_loss(const float* __restrict__ z, const float* __restrict__ cb,
                              const int* __restrict__ codes, float* __restrict__ outq,
                              double* __restrict__ loss) {
  const int gid = blockIdx.x * blockDim.x + threadIdx.x;
  const int e0 = gid * 4;
  const int row = e0 / DIM;
  const int col = e0 - row * DIM;
  const int c = codes[row];
  const float4 zv = *(const float4*)(z + e0);
  const float4 qv = *(const float4*)(cb + (size_t)c * DIM + col);
  float d0 = qv.x - zv.x, d1 = qv.y - zv.y, d2 = qv.z - zv.z, d3 = qv.w - zv.w;
  float4 ov = { zv.x + d0, zv.y + d1, zv.z + d2, zv.w + d3 };
  *(float4*)(outq + e0) = ov;
  double s = (double)(d0 * d0) + (double)(d1 * d1) + (double)(d2 * d2) + (double)(d3 * d3);
  #pragma unroll
  for (int off = 32; off; off >>= 1) s += __shfl_xor(s, off, 64);
  __shared__ double wsum[4];
  const int wave = threadIdx.x >> 6, lane = threadIdx.x & 63;
  if (lane == 0) wsum[wave] = s;
  __syncthreads();
  if (threadIdx.x == 0) atomicAdd(loss, wsum[0] + wsum[1] + wsum[2] + wsum[3]);
}

extern "C" void kernel_launch(void* const* d_in, const int* in_sizes, int n_in,
                              void* d_out, int out_size, void* d_ws, size_t ws_size,
                              hipStream_t stream) {
  const float* z  = (const float*)d_in[0];
  const float* cb = (const float*)d_in[1];
  float* out = (float*)d_out;          // [codes 4096][q_ste 3145728][loss 1]
  char* ws = (char*)d_ws;
  float*  zsq = (float*)(ws + WS_ZSQ);
  unsigned int* runmin = (unsigned int*)(ws + WS_RUNMIN);
  int* cnt     = (int*)(ws + WS_CNT);
  int* codes_i = (int*)(ws + WS_CODESI);
  double* loss = (double*)(ws + WS_LOSS);
  int* list    = (int*)(ws + WS_LIST);
  unsigned long long* keys = (unsigned long long*)(ws + WS_LIST);

  dim3 g1(NROWS / TM, KCODES / TC);

  if (ws_size >= WS_NEED) {
    half_t* Ahg = (half_t*)(ws + WS_AH);
    half_t* Bhg = (half_t*)(ws + WS_BH);
    k_convA<<<NROWS / 4, 256, 0, stream>>>(z, Ahg, zsq, runmin, cnt, loss);
    k_convB<<<(KCODES * DIM / 8 + 255) / 256, 256, 0, stream>>>(cb, Bhg, KCODES * DIM / 8);
    k1_s1<<<g1, 256, 0, stream>>>(Ahg, Bhg, zsq, runmin, cnt, list);
    k_refine<<<NROWS, 256, 0, stream>>>(z, cb, zsq, cnt, list, out, out + NROWS, loss);
  } else {
    k0_zsq<<<NROWS / 4, 256, 0, stream>>>(z, zsq, keys, loss);
    k1_mfma<<<g1, 256, 0, stream>>>(z, cb, zsq, keys);
    k2_codes<<<NROWS / 256, 256, 0, stream>>>(keys, out, codes_i);
    k3_quant_loss<<<(NROWS * DIM / 4) / 256, 256, 0, stream>>>(z, cb, codes_i, out + NROWS, loss);
  }

  k4_final<<<1, 1, 0, stream>>>(loss, out + NROWS + (size_t)NROWS * DIM);
}